// Round 20
// baseline (279.102 us; speedup 1.0000x reference)
//
#include <hip/hip_runtime.h>
#include <hip/hip_bf16.h>
#include <math.h>

using short8 = __attribute__((ext_vector_type(8))) short;
using f32x16 = __attribute__((ext_vector_type(16))) float;
using f32x2  = __attribute__((ext_vector_type(2))) float;

#define AS3 __attribute__((address_space(3)))
#define AS1 __attribute__((address_space(1)))

constexpr int B  = 1024;
constexpr int NN = 128;   // nodes per tree
constexpr int F  = 318;   // raw features

__device__ inline float bf2f(unsigned short u) {
    union { unsigned int i; float f; } x; x.i = ((unsigned int)u) << 16; return x.f;
}
__device__ inline unsigned short f2bf(float f) {
    union { float f; unsigned int i; } x; x.f = f;
    unsigned int r = x.i + 0x7fff + ((x.i >> 16) & 1);
    return (unsigned short)(r >> 16);
}

// ---------- ONE fused prepack kernel ----------
__global__ __launch_bounds__(256) void prepack_all(const float* __restrict__ enc_w,
                                                   const float* __restrict__ w1,
                                                   const float* __restrict__ w2,
                                                   const float* __restrict__ w3,
                                                   unsigned short* __restrict__ wpe,
                                                   unsigned short* __restrict__ wp1f,
                                                   unsigned short* __restrict__ wp2,
                                                   unsigned short* __restrict__ wp3)
{
    int t = blockIdx.x * 256 + threadIdx.x;
    if (t < 40960) {
        int j = t & 7;
        int lane = (t >> 3) & 63;
        int rest = t >> 9;                 // 0..79
        int ob = rest % 4;
        int kbg = rest / 4;                // 0..19
        int ks = kbg & 3;
        int cc = kbg >> 2;                 // 0..4
        int c = cc * 64 + ks * 16 + (lane >> 5) * 8 + j;
        int o = ob * 32 + (lane & 31);
        float v = (c < 318 && o < 109) ? enc_w[(size_t)o * 318 + c] : 0.f;
        wpe[t] = f2bf(v);
        return;
    }
    t -= 40960;
    if (t < 196608) {
        int j = t & 7;
        int lane = (t >> 3) & 63;
        int r = t >> 9;                    // 0..383
        int fp = r % 48;
        int oy = r / 48;
        int h   = fp / 24;
        int rem = fp % 24;
        int obp = rem & 1;
        int q   = rem >> 1;                // 0..11
        int ks2 = q & 3;
        int k   = q >> 2;
        int ks  = h * 4 + ks2;
        int p = ks * 16 + (lane >> 5) * 8 + j;                       // position 0..127
        int c = (p & 64) + ((p & 63) >> 1) + ((p & 1) << 5);         // permuted channel
        int o = oy * 64 + obp * 32 + (lane & 31);
        float v = (c < 109) ? w1[((size_t)o * 109 + c) * 3 + k] : 0.f;
        wp1f[t] = f2bf(v);
        return;
    }
    t -= 196608;
    if (t < 393216) {
        const int NCC = 16;                // 512/32
        int j = t & 7;
        int lane = (t >> 3) & 63;
        int r = t >> 9;
        int cb = r & 3; r >>= 2;
        int ks = r & 1; r >>= 1;
        int k = r % 3; r /= 3;
        int ci = r % NCC;
        int oy = r / NCC;
        int pos = ci * 32 + ks * 16 + (lane >> 5) * 8 + j;
        int c = (pos & ~63) | ((pos & 1) << 5) | ((pos >> 1) & 31);
        int o = oy * 128 + cb * 32 + (lane & 31);
        float v = (c < 512 && o < 256) ? w2[((size_t)o * 512 + c) * 3 + k] : 0.f;
        wp2[t] = f2bf(v);
        return;
    }
    t -= 393216;
    if (t < 98304) {
        const int NCC = 8;                 // 256/32
        int j = t & 7;
        int lane = (t >> 3) & 63;
        int r = t >> 9;
        int cb = r & 3; r >>= 2;
        int ks = r & 1; r >>= 1;
        int k = r % 3; r /= 3;
        int ci = r % NCC;
        int oy = r / NCC;
        int pos = ci * 32 + ks * 16 + (lane >> 5) * 8 + j;
        int c = (pos & ~63) | ((pos & 1) << 5) | ((pos >> 1) & 31);
        int o = oy * 128 + cb * 32 + (lane & 31);
        float v = (c < 256 && o < 128) ? w3[((size_t)o * 256 + c) * 3 + k] : 0.f;
        wp3[t] = f2bf(v);
    }
}

// ---------- FUSED encoder + conv1 ----------
// Phase 1: x0[b] -> Xt (32KB, permuted pair layout); 2-deep register prefetch of trees,
//          raw lgkm-only barriers (tree loads stay in flight across barriers).
// Phase 2: conv1 output-stationary; 24 gathered A-frags hoisted to regs; Xt then DEAD ->
//          reused as 3rd B buffer (3x24KB ring, 2-chunk-deep pipeline);
//          canonical wait(own,counted) -> barrier -> issue -> stores ordering.
__global__ __launch_bounds__(256, 2) void enc_conv1(const float* __restrict__ trees,
                                                    const int* __restrict__ idx,
                                                    const unsigned short* __restrict__ wpe,
                                                    const float* __restrict__ encb,
                                                    const unsigned short* __restrict__ wp1,
                                                    const float* __restrict__ b1,
                                                    unsigned short* __restrict__ y1,   // [B][NN][512] permuted
                                                    float* __restrict__ partials)
{
    __shared__ __align__(16) char gbuf[81920];
    char* Xt = gbuf;               // 32KB x0 tile (dead after areg hoist)
    char* W  = gbuf + 32768;       // 48KB: enc staging dbuf / conv1 B buffers

    const int b = blockIdx.x;
    const int tid = threadIdx.x;
    const int lane = tid & 63;
    const int wv = tid >> 6;
    const int l31 = lane & 31, lh2 = lane >> 5;

    // ---------------- phase 1: encoder ----------------
    {
        constexpr int CC = 64, NCH = 5, KS = 4, NB = 4;
        constexpr int BUFB = NN * CC * 2;   // 16 KB
        const int cp = tid >> 3;            // channel pair 0..31
        const int ng = tid & 7;             // node group of 16

        float4 uA[2][4], uB[2][4];
        auto load = [&](int ch, float4* A4, float4* B4) {
            const int c0 = ch * CC + 2 * cp, c1 = c0 + 1;
            const bool k0 = (c0 < F), k1 = (c1 < F);
            const float* s0 = trees + ((size_t)b * F + c0) * NN + ng * 16;
            const float* s1 = s0 + NN;
#pragma unroll
            for (int j = 0; j < 4; ++j) {
                A4[j] = k0 ? *reinterpret_cast<const float4*>(s0 + j * 4) : make_float4(0.f, 0.f, 0.f, 0.f);
                B4[j] = k1 ? *reinterpret_cast<const float4*>(s1 + j * 4) : make_float4(0.f, 0.f, 0.f, 0.f);
            }
        };
        const int gsw = cp >> 2;
        const int cby = (cp & 3) * 4;
        auto stor = [&](char* wb, const float4* A4, const float4* B4) {
            const float* fa = reinterpret_cast<const float*>(A4);
            const float* fb = reinterpret_cast<const float*>(B4);
#pragma unroll
            for (int i = 0; i < 16; ++i) {
                const int n = ng * 16 + i;
                unsigned int pk;
                asm("v_cvt_pk_bf16_f32 %0, %1, %2" : "=v"(pk) : "v"(fa[i]), "v"(fb[i]));
                int byte = n * 128 + (((gsw ^ (n & 7) ^ ng) << 4) + cby);
                *reinterpret_cast<unsigned int*>(wb + byte) = pk;
            }
        };

        f32x16 acc[NB];
#pragma unroll
        for (int ob = 0; ob < NB; ++ob) acc[ob] = (f32x16)0.f;

        const int nrow = wv * 32 + l31;
        const unsigned abyte = (unsigned)(nrow * 128);
        const unsigned axor = (unsigned)(((nrow & 7) ^ ((nrow >> 4) & 7)) << 4);

        load(0, uA[0], uB[0]);
        load(1, uA[1], uB[1]);
        stor(W, uA[0], uB[0]);
        asm volatile("s_waitcnt lgkmcnt(0)" ::: "memory");
        __builtin_amdgcn_s_barrier();
        __builtin_amdgcn_sched_barrier(0);

        int p = 0;
#pragma unroll
        for (int ch = 0; ch < NCH; ++ch) {
            if (ch + 2 < NCH) load(ch + 2, uA[ch & 1], uB[ch & 1]);   // 2-deep prefetch
            const char* base = W + p * BUFB;
            __builtin_amdgcn_s_setprio(1);
#pragma unroll
            for (int ks = 0; ks < KS; ++ks) {
                const int kbg = ch * KS + ks;
                short8 a = *reinterpret_cast<const short8*>(
                    base + abyte + (((unsigned)((ks * 2 + lh2) << 4)) ^ axor));
                const unsigned short* wb_ = wpe + ((size_t)(kbg * 4) * 64 + lane) * 8;
#pragma unroll
                for (int ob = 0; ob < NB; ++ob) {
                    short8 bf_ = *reinterpret_cast<const short8*>(wb_ + ob * 512);
                    acc[ob] = __builtin_amdgcn_mfma_f32_32x32x16_bf16(a, bf_, acc[ob], 0, 0, 0);
                }
            }
            __builtin_amdgcn_s_setprio(0);
            if (ch + 1 < NCH) {
                stor(W + (p ^ 1) * BUFB, uA[(ch + 1) & 1], uB[(ch + 1) & 1]);
                asm volatile("s_waitcnt lgkmcnt(0)" ::: "memory");
                __builtin_amdgcn_s_barrier();
                __builtin_amdgcn_sched_barrier(0);
            }
            p ^= 1;
        }

        // epilogue -> Xt, PERMUTED pair writes (b32, conflict-free)
        float bs[NB];
#pragma unroll
        for (int ob = 0; ob < NB; ++ob) {
            int c = ob * 32 + l31;
            bs[ob] = (c < 109) ? encb[c] : 0.f;
        }
#pragma unroll
        for (int r = 0; r < 16; ++r) {
            const int row = wv * 32 + (r & 3) + 8 * (r >> 2) + 4 * lh2;
            unsigned int pk0, pk1;
            float a0 = acc[0][r] + bs[0], a1 = acc[1][r] + bs[1];
            float a2 = acc[2][r] + bs[2], a3 = acc[3][r] + bs[3];
            asm("v_cvt_pk_bf16_f32 %0, %1, %2" : "=v"(pk0) : "v"(a0), "v"(a1));
            asm("v_cvt_pk_bf16_f32 %0, %1, %2" : "=v"(pk1) : "v"(a2), "v"(a3));
            int by0 = row * 256 + ((((l31 >> 2) ^ (row & 15)) << 4) | ((l31 & 3) * 4));
            int by1 = row * 256 + ((((8 + (l31 >> 2)) ^ (row & 15)) << 4) | ((l31 & 3) * 4));
            *reinterpret_cast<unsigned int*>(Xt + by0) = pk0;
            *reinterpret_cast<unsigned int*>(Xt + by1) = pk1;
        }
        __syncthreads();
    }

    // ---------------- phase 2: conv1 ----------------
    const int nrowA = wv * 32 + l31;
    unsigned aab[3], axm[3];
#pragma unroll
    for (int k = 0; k < 3; ++k) {
        int s_ = idx[b * 3 * NN + 3 * nrowA + k];
        aab[k] = (unsigned)(s_ * 256);
        axm[k] = (unsigned)(s_ & 15);
    }

    // hoist ALL 24 gathered A-frags into registers (read each once); Xt dead after this
    short8 areg[24];
#pragma unroll
    for (int h = 0; h < 2; ++h)
#pragma unroll
        for (int ks2 = 0; ks2 < 4; ++ks2)
#pragma unroll
            for (int k = 0; k < 3; ++k) {
                const unsigned slot = ((unsigned)((h * 4 + ks2) * 2 + lh2)) ^ axm[k];
                areg[(h * 4 + ks2) * 3 + k] =
                    *reinterpret_cast<const short8*>(Xt + aab[k] + (slot << 4));
            }
    asm volatile("s_waitcnt lgkmcnt(0)" ::: "memory");   // areg reads complete
    __builtin_amdgcn_s_barrier();                         // all waves done reading Xt
    __builtin_amdgcn_sched_barrier(0);

    char* bufs[3] = {W, W + 24576, Xt};                   // 3x24KB ring
    auto issueBh = [&](int ht) {
        const unsigned short* src = wp1 + (size_t)ht * 24 * 512;
        char* dst = bufs[ht % 3];
#pragma unroll
        for (int i = 0; i < 6; ++i)
            __builtin_amdgcn_global_load_lds(
                (const AS1 void*)(src + (i * 256 + tid) * 8),
                (AS3 void*)(dst + (i * 256 + wv * 64) * 16),
                16, 0, 0);
    };

    unsigned int* y1w = reinterpret_cast<unsigned int*>(y1);
    float tsum = 0.f, tss = 0.f;

    issueBh(0);
    issueBh(1);
    issueBh(2);
    asm volatile("s_waitcnt vmcnt(12)" ::: "memory");     // own L0 landed
    __builtin_amdgcn_s_barrier();                         // all waves' L0 landed
    __builtin_amdgcn_sched_barrier(0);

    f32x16 acc[2];
#pragma unroll
    for (int ht = 0; ht < 16; ++ht) {
        const int h = ht & 1, oy = ht >> 1;
        const char* bp = bufs[ht % 3];
        if (h == 0) {
#pragma unroll
            for (int obp = 0; obp < 2; ++obp) {
                const float bv = b1[oy * 64 + obp * 32 + l31];
#pragma unroll
                for (int r = 0; r < 16; ++r) acc[obp][r] = bv;
            }
        }
        __builtin_amdgcn_s_setprio(1);
#pragma unroll
        for (int ks2 = 0; ks2 < 4; ++ks2) {
#pragma unroll
            for (int k = 0; k < 3; ++k) {
                short8 a = areg[(h * 4 + ks2) * 3 + k];
#pragma unroll
                for (int obp = 0; obp < 2; ++obp) {
                    short8 bf_ = *reinterpret_cast<const short8*>(
                        bp + (((k * 4 + ks2) * 2 + obp) << 10) + lane * 16);
                    acc[obp] = __builtin_amdgcn_mfma_f32_32x32x16_bf16(a, bf_, acc[obp], 0, 0, 0);
                }
            }
        }
        __builtin_amdgcn_s_setprio(0);

        if (ht + 1 < 16) {
            // wait own L(ht+1) (issued 2 iterations ago) -> FIFO-derived counts
            if (ht == 0 || ht == 1) { asm volatile("s_waitcnt vmcnt(6)  lgkmcnt(0)" ::: "memory"); }
            else if (ht == 14)      { asm volatile("s_waitcnt vmcnt(16) lgkmcnt(0)" ::: "memory"); }
            else                    { asm volatile("s_waitcnt vmcnt(22) lgkmcnt(0)" ::: "memory"); }
            __builtin_amdgcn_s_barrier();     // cross-wave: chunk ht+1 fully landed; buf ht%3 free
            __builtin_amdgcn_sched_barrier(0);
            if (ht + 3 < 16) issueBh(ht + 3);
        }

        if (h == 1) {
            // stats + permuted dword stores
#pragma unroll
            for (int r = 0; r < 16; ++r) {
                float v0_ = acc[0][r], v1_ = acc[1][r];
                tsum += v0_ + v1_;
                tss  += v0_ * v0_ + v1_ * v1_;
                unsigned int pk;
                asm("v_cvt_pk_bf16_f32 %0, %1, %2" : "=v"(pk) : "v"(v0_), "v"(v1_));
                int row = wv * 32 + (r & 3) + 8 * (r >> 2) + 4 * lh2;
                y1w[((size_t)b * NN + row) * 256 + oy * 32 + l31] = pk;
            }
        }
    }

    __syncthreads();
    float* rbuf = reinterpret_cast<float*>(W);
#pragma unroll
    for (int ss = 32; ss; ss >>= 1) { tsum += __shfl_down(tsum, ss); tss += __shfl_down(tss, ss); }
    if (lane == 0) { rbuf[wv * 2] = tsum; rbuf[wv * 2 + 1] = tss; }
    __syncthreads();
    if (tid == 0) {
        float sm = rbuf[0] + rbuf[2] + rbuf[4] + rbuf[6];
        float q = rbuf[1] + rbuf[3] + rbuf[5] + rbuf[7];
        partials[2 * b] = sm;
        partials[2 * b + 1] = q;
    }
}

// ---------- conv2/conv3: output-stationary, A-side LDS gather, OT=128, CC=32 ----------
template <int CIN, int OTN, int COUT, bool COLMAX>
__global__ __launch_bounds__(256, 2) void conv_gemm(const unsigned short* __restrict__ xin,
                                                    const int* __restrict__ idx,
                                                    const unsigned short* __restrict__ wp,
                                                    const float* __restrict__ bias,
                                                    const float* __restrict__ stats,
                                                    unsigned short* __restrict__ yout,
                                                    float* __restrict__ colmax,
                                                    float* __restrict__ partials)
{
    constexpr int CC    = 32;
    constexpr int NCC   = CIN / CC;
    constexpr int AIT   = 2;
    constexpr int ABUF  = NN * 128;
    constexpr int BFR   = 2 * 3 * 4;
    constexpr int BBUF  = BFR * 1024;
    constexpr int BIT   = 6;
    constexpr int BUFB  = ABUF + BBUF;

    __shared__ __align__(16) char gbuf[81920];
    float (*cmax)[2][32] = reinterpret_cast<float (*)[2][32]>(gbuf + 79872);
    float* rbuf = reinterpret_cast<float*>(gbuf + 81408);

    const int f  = blockIdx.x;
    const int s  = f >> 3;
    const int b  = (f & 7) + 8 * (s / OTN);
    const int oy = s % OTN;

    const int tid = threadIdx.x;
    const int lane = tid & 63;
    const int wv = tid >> 6;
    const int wm = wv >> 1, wn = wv & 1;
    const int l31 = lane & 31, lh2 = lane >> 5;

    const float mu = stats[0], inv = stats[1];
    const float nmi = -mu * inv;

    const unsigned short* xb = xin + (size_t)b * NN * CIN;

    unsigned aab[2][3], axm[2][3];
#pragma unroll
    for (int nf = 0; nf < 2; ++nf) {
        const int n = wm * 64 + nf * 32 + l31;
#pragma unroll
        for (int k = 0; k < 3; ++k) {
            int s_ = idx[b * 3 * NN + 3 * n + k];
            aab[nf][k] = (unsigned)(s_ * 128);
            axm[nf][k] = (unsigned)(s_ & 7);
        }
    }

    f32x16 acc[2][2];
#pragma unroll
    for (int nf = 0; nf < 2; ++nf)
#pragma unroll
        for (int nc = 0; nc < 2; ++nc) {
            const float bv = bias[oy * 128 + wn * 64 + nc * 32 + l31];
#pragma unroll
            for (int r = 0; r < 16; ++r) acc[nf][nc][r] = bv;
        }

    auto issueB = [&](int ci, char* dst) {
        const unsigned short* src = wp + ((size_t)(oy * NCC + ci)) * (BFR * 512);
#pragma unroll
        for (int i = 0; i < BIT; ++i)
            __builtin_amdgcn_global_load_lds(
                (const AS1 void*)(src + (i * 256 + tid) * 8),
                (AS3 void*)(dst + (i * 256 + wv * 64) * 16),
                16, 0, 0);
    };
    unsigned ngoff[AIT], lby[AIT];
#pragma unroll
    for (int i = 0; i < AIT; ++i) {
        int it = i * 256 + tid;
        int n = it >> 2, g = it & 3;
        ngoff[i] = (unsigned)(n * CIN + g * 8);
        lby[i]   = (unsigned)(n * 128 + ((g ^ (n & 7)) << 4));
    }
    auto loadA = [&](int cc, uint4* vv) {
#pragma unroll
        for (int i = 0; i < AIT; ++i)
            vv[i] = *reinterpret_cast<const uint4*>(xb + cc * CC + ngoff[i]);
    };
    const f32x2 iv2 = {inv, inv}, nm2 = {nmi, nmi};
    auto storA = [&](char* wb, const uint4* vv) {
#pragma unroll
        for (int i = 0; i < AIT; ++i) {
            uint4 t = vv[i];
            unsigned int* pw = reinterpret_cast<unsigned int*>(&t);
#pragma unroll
            for (int q = 0; q < 4; ++q) {
                unsigned int u = pw[q];
                f32x2 sv, d;
                sv[0] = __uint_as_float(u << 16);
                sv[1] = __uint_as_float(u & 0xffff0000u);
                asm("v_pk_fma_f32 %0, %1, %2, %3" : "=v"(d) : "v"(sv), "v"(iv2), "v"(nm2));
                float f0 = fmaxf(d[0], 0.f);
                float f1 = fmaxf(d[1], 0.f);
                unsigned int r;
                asm("v_cvt_pk_bf16_f32 %0, %1, %2" : "=v"(r) : "v"(f0), "v"(f1));
                pw[q] = r;
            }
            *reinterpret_cast<uint4*>(wb + lby[i]) = t;
        }
    };

    uint4 v0[AIT], v1[AIT];

    issueB(0, gbuf + ABUF);
    loadA(0, v0);
    loadA(1, v1);
    storA(gbuf, v0);
    asm volatile("s_waitcnt lgkmcnt(0)" ::: "memory");
    __builtin_amdgcn_s_barrier();
    __builtin_amdgcn_sched_barrier(0);

#pragma unroll
    for (int cc = 0; cc < NCC; ++cc) {
        const int p = cc & 1;
        if (cc + 1 < NCC) {
            issueB(cc + 1, gbuf + (p ^ 1) * BUFB + ABUF);
            if (cc + 2 < NCC) loadA(cc + 2, (cc & 1) ? v1 : v0);
        }
        const char* ab = gbuf + p * BUFB;
        const char* bb = ab + ABUF;
        __builtin_amdgcn_s_setprio(1);
#pragma unroll
        for (int ks = 0; ks < 2; ++ks) {
            const unsigned s0 = (unsigned)(ks * 2 + lh2);
#pragma unroll
            for (int k = 0; k < 3; ++k) {
                short8 a0 = *reinterpret_cast<const short8*>(ab + aab[0][k] + ((s0 ^ axm[0][k]) << 4));
                short8 a1 = *reinterpret_cast<const short8*>(ab + aab[1][k] + ((s0 ^ axm[1][k]) << 4));
#pragma unroll
                for (int nc = 0; nc < 2; ++nc) {
                    short8 bf_ = *reinterpret_cast<const short8*>(
                        bb + (((k * 2 + ks) * 4 + wn * 2 + nc) << 10) + lane * 16);
                    acc[0][nc] = __builtin_amdgcn_mfma_f32_32x32x16_bf16(a0, bf_, acc[0][nc], 0, 0, 0);
                    acc[1][nc] = __builtin_amdgcn_mfma_f32_32x32x16_bf16(a1, bf_, acc[1][nc], 0, 0, 0);
                }
            }
        }
        __builtin_amdgcn_s_setprio(0);
        if (cc + 1 < NCC) storA(gbuf + (p ^ 1) * BUFB, (cc & 1) ? v0 : v1);

        if (cc + 1 < NCC) {
            if (cc + 2 < NCC) {
                asm volatile("s_waitcnt vmcnt(2) lgkmcnt(0)" ::: "memory");
            } else {
                asm volatile("s_waitcnt vmcnt(0) lgkmcnt(0)" ::: "memory");
            }
            __builtin_amdgcn_s_barrier();
            __builtin_amdgcn_sched_barrier(0);
        } else {
            asm volatile("s_waitcnt lgkmcnt(0)" ::: "memory");
            __builtin_amdgcn_s_barrier();
            __builtin_amdgcn_sched_barrier(0);
        }
    }

    float tsum = 0.f, tss = 0.f;

    if (COLMAX) {
        float m[2] = {-1e30f, -1e30f};
#pragma unroll
        for (int nf = 0; nf < 2; ++nf)
#pragma unroll
            for (int nc = 0; nc < 2; ++nc)
#pragma unroll
                for (int r = 0; r < 16; ++r) {
                    float val = acc[nf][nc][r];
                    tsum += val; tss += val * val;
                    m[nc] = fmaxf(m[nc], val);
                }
#pragma unroll
        for (int nc = 0; nc < 2; ++nc) m[nc] = fmaxf(m[nc], __shfl_xor(m[nc], 32));
        if (lh2 == 0) {
#pragma unroll
            for (int nc = 0; nc < 2; ++nc) cmax[wv][nc][l31] = m[nc];
        }
        __syncthreads();
        if (tid < 128) {
            const int c = tid;
            const int wn_ = (c >> 6) & 1, nc_ = (c >> 5) & 1, l_ = c & 31;
            float mm = fmaxf(cmax[wn_][nc_][l_], cmax[2 + wn_][nc_][l_]);
            colmax[b * COUT + c] = mm;
        }
    } else {
        unsigned int* yw = reinterpret_cast<unsigned int*>(yout);
#pragma unroll
        for (int nf = 0; nf < 2; ++nf)
#pragma unroll
            for (int r = 0; r < 16; ++r) {
                float v0_ = acc[nf][0][r], v1_ = acc[nf][1][r];
                tsum += v0_ + v1_;
                tss  += v0_ * v0_ + v1_ * v1_;
                unsigned int pk;
                asm("v_cvt_pk_bf16_f32 %0, %1, %2" : "=v"(pk) : "v"(v0_), "v"(v1_));
                int row = wm * 64 + nf * 32 + (r & 3) + 8 * (r >> 2) + 4 * lh2;
                yw[((size_t)b * NN + row) * (COUT / 2) + oy * 64 + wn * 32 + l31] = pk;
            }
    }

#pragma unroll
    for (int ss = 32; ss; ss >>= 1) { tsum += __shfl_down(tsum, ss); tss += __shfl_down(tss, ss); }
    __syncthreads();
    if (lane == 0) { rbuf[wv * 2] = tsum; rbuf[wv * 2 + 1] = tss; }
    __syncthreads();
    if (tid == 0) {
        float sm = rbuf[0] + rbuf[2] + rbuf[4] + rbuf[6];
        float q = rbuf[1] + rbuf[3] + rbuf[5] + rbuf[7];
        int gid = oy * B + b;
        partials[2 * gid] = sm;
        partials[2 * gid + 1] = q;
    }
}

// ---------- finalize global layernorm stats ----------
__global__ __launch_bounds__(256) void stats_kernel(const float* __restrict__ partials,
                                                    float* __restrict__ stats,
                                                    int npart, double ntot)
{
    __shared__ double sd[256], sd2[256];
    double s = 0.0, s2 = 0.0;
    for (int i = threadIdx.x; i < npart; i += 256) { s += (double)partials[2 * i]; s2 += (double)partials[2 * i + 1]; }
    sd[threadIdx.x] = s; sd2[threadIdx.x] = s2;
    __syncthreads();
    for (int k = 128; k > 0; k >>= 1) {
        if (threadIdx.x < k) { sd[threadIdx.x] += sd[threadIdx.x + k]; sd2[threadIdx.x] += sd2[threadIdx.x + k]; }
        __syncthreads();
    }
    if (threadIdx.x == 0) {
        double mu = sd[0] / ntot;
        double var = (sd2[0] - sd[0] * sd[0] / ntot) / (ntot - 1.0);
        double sdv = sqrt(var > 0.0 ? var : 0.0);
        stats[0] = (float)mu;
        stats[1] = (float)(1.0 / (sdv + 1e-5));
    }
}

// ---------- pool + heads WITH fused conv3-stats (per-block redundant reduce) ----------
__global__ __launch_bounds__(256) void pool_head_kernel(const float* __restrict__ partials, // conv3 partials [1024][2]
                                                        const float* __restrict__ colmax,   // [B][128]
                                                        const float* __restrict__ latw,
                                                        const float* __restrict__ latb,
                                                        const float* __restrict__ costw,
                                                        const float* __restrict__ costb,
                                                        float* __restrict__ out)
{
    __shared__ double sd[256], sd2[256];
    __shared__ float pl[128];
    __shared__ float st[2];
    const int b = blockIdx.x, t = threadIdx.x;

    double s = 0.0, s2 = 0.0;
#pragma unroll
    for (int i = 0; i < 4; ++i) {
        int p = t + i * 256;
        s  += (double)partials[2 * p];
        s2 += (double)partials[2 * p + 1];
    }
    sd[t] = s; sd2[t] = s2;
    __syncthreads();
    for (int k = 128; k > 0; k >>= 1) {
        if (t < k) { sd[t] += sd[t + k]; sd2[t] += sd2[t + k]; }
        __syncthreads();
    }
    if (t == 0) {
        const double ntot = 16777216.0;   // B*128*NN
        double mu = sd[0] / ntot;
        double var = (sd2[0] - sd[0] * sd[0] / ntot) / (ntot - 1.0);
        double sdv = sqrt(var > 0.0 ? var : 0.0);
        st[0] = (float)mu;
        st[1] = (float)(1.0 / (sdv + 1e-5));
    }
    __syncthreads();
    const float mu = st[0], inv = st[1];

    if (t < 128) pl[t] = fmaxf((colmax[b * 128 + t] - mu) * inv, 0.f);
    __syncthreads();
    if (t < 128) {
        const float* w = (t < 64) ? latw : costw;
        const int l = t & 63;
        float v = pl[l] * w[l] + pl[l + 64] * w[l + 64];
#pragma unroll
        for (int s_ = 32; s_ > 0; s_ >>= 1) v += __shfl_down(v, s_);
        if (l == 0) {
            const float bb = (t < 64) ? latb[0] : costb[0];
            out[(t < 64 ? 0 : B) + b] = 1.f / (1.f + expf(-(v + bb)));
        }
    }
}

// ---------- launch ----------
extern "C" void kernel_launch(void* const* d_in, const int* in_sizes, int n_in,
                              void* d_out, int out_size, void* d_ws, size_t ws_size,
                              hipStream_t stream)
{
    (void)in_sizes; (void)n_in; (void)out_size; (void)ws_size;
    const float* trees   = (const float*)d_in[0];
    const int*   indexes = (const int*)  d_in[1];
    const float* enc_w   = (const float*)d_in[2];
    const float* enc_b   = (const float*)d_in[3];
    const float* w1 = (const float*)d_in[4];
    const float* b1 = (const float*)d_in[5];
    const float* w2 = (const float*)d_in[6];
    const float* b2 = (const float*)d_in[7];
    const float* w3 = (const float*)d_in[8];
    const float* b3 = (const float*)d_in[9];
    const float* lat_w  = (const float*)d_in[10];
    const float* lat_b  = (const float*)d_in[11];
    const float* cost_w = (const float*)d_in[12];
    const float* cost_b = (const float*)d_in[13];
    float* out = (float*)d_out;

    char* ws = (char*)d_ws;
    size_t off = 0;
    auto alloc = [&](size_t bytes) -> char* {
        char* p = ws + off;
        off += (bytes + 255) & ~(size_t)255;
        return p;
    };
    unsigned short* wpe  = (unsigned short*)alloc((size_t)40960 * 2);
    unsigned short* wp1f = (unsigned short*)alloc((size_t)196608 * 2);
    unsigned short* wp2  = (unsigned short*)alloc((size_t)393216 * 2);
    unsigned short* wp3  = (unsigned short*)alloc((size_t)98304 * 2);
    unsigned short* y1   = (unsigned short*)alloc((size_t)B * NN * 512 * 2);
    unsigned short* y2   = (unsigned short*)alloc((size_t)B * NN * 256 * 2);
    float* colmax   = (float*)alloc((size_t)B * 128 * 4);
    float* partials = (float*)alloc((size_t)8192 * 2 * 4);
    float* stats    = (float*)alloc(8 * 4);

    float* part1 = partials;              // enc_conv1: 1024 pairs
    float* part2 = partials + 2048 * 2;   // conv2: 2048 pairs
    float* part3 = partials + 6144 * 2;   // conv3: 1024 pairs

    prepack_all<<<dim3(2848), dim3(256), 0, stream>>>(enc_w, w1, w2, w3, wpe, wp1f, wp2, wp3);

    // FUSED encoder + conv1 (permuted y1; x0 never leaves LDS; A hoisted; 3-buffer B ring)
    enc_conv1<<<dim3(B), dim3(256), 0, stream>>>(trees, indexes, wpe, enc_b, wp1f, b1, y1, part1);
    stats_kernel<<<dim3(1), dim3(256), 0, stream>>>(part1, stats + 0, 1024, (double)((size_t)B * 512 * NN));

    // conv2: output-stationary, OT=128, 2 o-tiles; permuted in/out
    conv_gemm<512, 2, 256, false>
        <<<dim3(B * 2), dim3(256), 0, stream>>>(y1, indexes, wp2, b2, stats + 0, y2, colmax, part2);
    stats_kernel<<<dim3(1), dim3(256), 0, stream>>>(part2, stats + 2, 2048, (double)((size_t)B * 256 * NN));

    // conv3: output-stationary, OT=128, colmax fused; permuted in
    conv_gemm<256, 1, 128, true>
        <<<dim3(B), dim3(256), 0, stream>>>(y2, indexes, wp3, b3, stats + 2, nullptr, colmax, part3);

    // pool + heads with fused conv3 stats
    pool_head_kernel<<<dim3(B), dim3(256), 0, stream>>>(part3, colmax, lat_w, lat_b, cost_w, cost_b, out);
}